// Round 3
// baseline (206.292 us; speedup 1.0000x reference)
//
#include <hip/hip_runtime.h>
#include <hip/hip_bf16.h>

// GatherBlock: out[m, c, y, xw] = x[b[m], c, yb[m]*16 + y, xb[m]*16 + xw]
// N=8, C=64, H=256, W=256, BH=BW=16, M=1024. fp32.
//
// v2b: 4 float4 per thread (MLP=4 independent loads before the stores) +
// non-temporal stores (output is streaming; keep L2/L3 for the gathered
// input which has duplicate-block reuse). Native ext_vector_type because
// __builtin_nontemporal_store rejects HIP_vector_type<float,4>.
// Grid: 4096 blocks of 256. m = blockIdx.x >> 2 is block-uniform ->
// idx loads are scalar s_loads.

typedef float vfloat4 __attribute__((ext_vector_type(4)));

__global__ __launch_bounds__(256) void gather_block_kernel(
    const vfloat4* __restrict__ x,
    const int* __restrict__ idx,
    vfloat4* __restrict__ out) {
  const int m  = blockIdx.x >> 2;
  const int b  = idx[3 * m + 0];
  const int yb = idx[3 * m + 1];
  const int xb = idx[3 * m + 2];

  // this block covers inner = [(blockIdx.x&3)*1024, +1024), 4 per thread
  const int base_inner = ((blockIdx.x & 3) << 10) | threadIdx.x;

  // base address (float4 units) of this m's block: (b*C*H + yb*16)*64 + xb*4
  const long long xbase =
      ((long long)(b << 6) * 256 + (yb << 4)) * 64 + (xb << 2);

  vfloat4 v[4];
#pragma unroll
  for (int k = 0; k < 4; ++k) {
    const int inner = base_inner + (k << 8);     // +256 per k -> c += 4
    const int xw4 = inner & 3;                   // float4 col in block row
    const int y   = (inner >> 2) & 15;           // row in block
    const int c   = inner >> 6;                  // channel
    v[k] = x[xbase + ((long long)c * 256 + y) * 64 + xw4];
  }

#pragma unroll
  for (int k = 0; k < 4; ++k) {
    __builtin_nontemporal_store(
        v[k], &out[((long long)m << 12) + base_inner + (k << 8)]);
  }
}

extern "C" void kernel_launch(void* const* d_in, const int* in_sizes, int n_in,
                              void* d_out, int out_size, void* d_ws, size_t ws_size,
                              hipStream_t stream) {
  const vfloat4* x = (const vfloat4*)d_in[0];
  const int* idx   = (const int*)d_in[1];
  vfloat4* out     = (vfloat4*)d_out;

  // M * (C*BH*BW/4 float4) / (256 threads * 4 per thread) = 4096 blocks
  gather_block_kernel<<<4096, 256, 0, stream>>>(x, idx, out);
}